// Round 11
// baseline (277.013 us; speedup 1.0000x reference)
//
#include <hip/hip_runtime.h>

typedef __attribute__((ext_vector_type(8))) short bhalf8;
typedef __attribute__((ext_vector_type(4))) float floatx4;

#define MFMA16 __builtin_amdgcn_mfma_f32_16x16x32_bf16
#define SCALE_EXP2 0.07362225f          // 384^-0.5 * log2(e), folded into Q

__device__ __forceinline__ unsigned short f2bf(float f) {
  union { float fl; unsigned u; } v;
  v.fl = f;
  unsigned r = v.u + 0x7fffu + ((v.u >> 16) & 1u);
  return (unsigned short)(r >> 16);
}
__device__ __forceinline__ unsigned fbits(float f) {
  union { float fl; unsigned u; } v; v.fl = f; return v.u;
}

typedef const __attribute__((address_space(1))) unsigned int* gas1_t;
typedef __attribute__((address_space(3))) unsigned int* las3_t;
// async global->LDS, 16 B per lane; LDS dest = wave-uniform base + lane*16
__device__ __forceinline__ void async16(const void* g, void* l) {
  __builtin_amdgcn_global_load_lds((gas1_t)g, (las3_t)l, 16, 0, 0);
}

struct __align__(8) us4 { unsigned short x, y, z, w; };

// ---------------- weights fp32->bf16 + conv-weight transpose/BN-fold ----------------
// fx layout (floats): per-cv contiguous block of 4224 floats (1056 float4):
//   [cv*4224 + i*384 + c]  i<9  : transposed conv taps
//   [cv*4224 + 3456 + c]         : inv scale
//   [cv*4224 + 3840 + c]         : shift
__global__ __launch_bounds__(256) void cvtw_prep_kernel(
    const float* __restrict__ wq, const float* __restrict__ wk,
    const float* __restrict__ wv, const float* __restrict__ wp,
    unsigned short* __restrict__ o,
    const float* __restrict__ cwq, const float* __restrict__ gq,
    const float* __restrict__ bq,  const float* __restrict__ mq,
    const float* __restrict__ vq,
    const float* __restrict__ cwk, const float* __restrict__ gk,
    const float* __restrict__ bk,  const float* __restrict__ mk,
    const float* __restrict__ vk,
    const float* __restrict__ cwv, const float* __restrict__ gv,
    const float* __restrict__ bv,  const float* __restrict__ mv,
    const float* __restrict__ vv,
    float* __restrict__ fx) {
  if (blockIdx.x < 576) {
    int i = blockIdx.x * 256 + threadIdx.x;
    o[i]          = f2bf(wq[i]);
    o[147456 + i] = f2bf(wk[i]);
    o[294912 + i] = f2bf(wv[i]);
    o[442368 + i] = f2bf(wp[i]);
    return;
  }
  const float* cw[3] = {cwq, cwk, cwv};
  const float* gg[3] = {gq, gk, gv};
  const float* bb[3] = {bq, bk, bv};
  const float* mm[3] = {mq, mk, mv};
  const float* vr[3] = {vq, vk, vv};
  for (int c = threadIdx.x; c < 384; c += 256) {
#pragma unroll
    for (int cv = 0; cv < 3; ++cv) {
#pragma unroll
      for (int i = 0; i < 9; ++i) fx[cv * 4224 + i * 384 + c] = cw[cv][c * 9 + i];
      float inv = gg[cv][c] * rsqrtf(vr[cv][c] + 1e-5f);
      fx[cv * 4224 + 3456 + c] = inv;
      fx[cv * 4224 + 3840 + c] = bb[cv][c] - mm[cv][c] * inv;
    }
  }
}

// ---- depthwise 3x3 conv + BN; 4 output rows/thread, taps loaded once, 18-deep MLP ----
// Outputs are pure streaming writes (re-read only a kernel later, >> L2 lifetime):
// non-temporal stores keep the 57 MB write stream from evicting the 9x-reused taps.
__global__ __launch_bounds__(384) void dwconv_bn_kernel(
    const float* __restrict__ x, const float* __restrict__ fx,
    unsigned short* __restrict__ qt, unsigned short* __restrict__ kt,
    unsigned short* __restrict__ vt) {
  __shared__ __align__(16) float4 Wl[3168];   // 50688 B, fx image
  const int tid = threadIdx.x;
  const int tok = tid / 96;
  const int g   = tid - tok * 96;
  int blk = blockIdx.x;                  // b*49 + yp*7 + xg
  int b   = blk / 49;
  int rr  = blk - b * 49;
  int yp  = rr / 7;
  int xg  = rr - yp * 7;
  int y0  = yp * 4;
  int xx  = xg * 4 + tok;
  const float4* xv = (const float4*)x;
  float4 z4 = {0.f, 0.f, 0.f, 0.f};
  float4 tap[6][3];                      // rows y0-1..y0+4, cols xx-1..xx+1
#pragma unroll
  for (int dy = 0; dy < 6; ++dy)
#pragma unroll
    for (int dx = 0; dx < 3; ++dx) {
      int yy = y0 - 1 + dy, xc = xx - 1 + dx;
      bool ok = ((unsigned)yy < 28u) & ((unsigned)xc < 28u);
      tap[dy][dx] = ok ? xv[((size_t)b * 784 + yy * 28 + xc) * 96 + g] : z4;
    }
  const float4* fxv = (const float4*)fx;
  for (int i = tid; i < 3168; i += 384) Wl[i] = fxv[i];
  __syncthreads();
  floatx4 acc[3][4];
#pragma unroll
  for (int cv = 0; cv < 3; ++cv)
#pragma unroll
    for (int j = 0; j < 4; ++j) acc[cv][j] = (floatx4){0.f, 0.f, 0.f, 0.f};
#pragma unroll
  for (int i = 0; i < 9; ++i) {
    int dy = i / 3, dx = i - dy * 3;
    float4 w0 = Wl[i * 96 + g];
    float4 w1 = Wl[1056 + i * 96 + g];
    float4 w2 = Wl[2112 + i * 96 + g];
#pragma unroll
    for (int j = 0; j < 4; ++j) {
      float4 t = tap[j + dy][dx];
      acc[0][j][0] += t.x * w0.x; acc[0][j][1] += t.y * w0.y;
      acc[0][j][2] += t.z * w0.z; acc[0][j][3] += t.w * w0.w;
      acc[1][j][0] += t.x * w1.x; acc[1][j][1] += t.y * w1.y;
      acc[1][j][2] += t.z * w1.z; acc[1][j][3] += t.w * w1.w;
      acc[2][j][0] += t.x * w2.x; acc[2][j][1] += t.y * w2.y;
      acc[2][j][2] += t.z * w2.z; acc[2][j][3] += t.w * w2.w;
    }
  }
  unsigned short* outs[3] = {qt, kt, vt};
  size_t o0 = ((size_t)b * 784 + y0 * 28 + xx) * 96 + g;   // us4 units
#pragma unroll
  for (int cv = 0; cv < 3; ++cv) {
    float4 inv = Wl[cv * 1056 + 864 + g];
    float4 sh  = Wl[cv * 1056 + 960 + g];
#pragma unroll
    for (int j = 0; j < 4; ++j) {
      unsigned lo = ((unsigned)f2bf(acc[cv][j][1] * inv.y + sh.y) << 16) |
                    f2bf(acc[cv][j][0] * inv.x + sh.x);
      unsigned hi = ((unsigned)f2bf(acc[cv][j][3] * inv.w + sh.w) << 16) |
                    f2bf(acc[cv][j][2] * inv.z + sh.z);
      unsigned long long pk = ((unsigned long long)hi << 32) | lo;
      __builtin_nontemporal_store(
          pk, (unsigned long long*)&((us4*)outs[cv])[o0 + (size_t)j * 28 * 96]);
    }
  }
}

// ---------------- 128x128 GEMM, merged QKV (mode 0, z-dispatch) / proj (mode 1) ------
// blockIdx (x,y) remapped XCD-chunked so the 3 nb-blocks sharing an A row-panel land
// on the same XCD's L2. Bijective for ANY z-phase: chunk capacity of each actual XCD
// equals the exact count of blocks landing there (prefix-sum over per-residue counts).
__global__ __launch_bounds__(256) void gemm128_kernel(
    const unsigned short* __restrict__ A0, const unsigned short* __restrict__ A1,
    const unsigned short* __restrict__ A2, const unsigned short* __restrict__ wbf,
    const float* __restrict__ bias,
    unsigned short* __restrict__ qh, unsigned short* __restrict__ kh,
    unsigned short* __restrict__ vht, float* __restrict__ dout, int mode) {
  __shared__ __align__(16) unsigned short SB[17408];  // Al | Bl ; reused as Ct[128][136]
  unsigned short* Al = SB;
  unsigned short* Bl = SB + 8192;
  const unsigned short* A;
  const unsigned short* W;
  int epi;
  float osc = 1.f;
  unsigned short* outb = nullptr;
  if (mode == 0) {
    int z = blockIdx.z;
    A = (z == 0) ? A0 : ((z == 1) ? A1 : A2);
    W = wbf + z * 147456;
    epi = (z == 2) ? 1 : 0;
    outb = (z == 0) ? qh : ((z == 1) ? kh : vht);
    if (z == 0) osc = SCALE_EXP2;        // fold softmax scale+log2e into Q
  } else {
    A = A0; W = wbf + 442368; epi = 2;
  }
  // bijective XCD-chunked remap of the (x,y) block space
  const int nwg  = gridDim.x * gridDim.y;
  const int orig = blockIdx.y * gridDim.x + blockIdx.x;
  const int qq = nwg >> 3, rr8 = nwg & 7;
  const int sft = (int)((unsigned)(blockIdx.z * nwg) & 7u);  // z-phase of linear id
  const int xcd = (orig + sft) & 7;                          // actual XCD of this block
  int base = 0;
  for (int c = 0; c < xcd; ++c) base += qq + ((((c - sft) & 7) < rr8) ? 1 : 0);
  const int nid = base + (orig >> 3);
  const int nb = (nid % gridDim.x) * 128, mb = (nid / gridDim.x) * 128;
  const int tid = threadIdx.x, lane = tid & 63;
  const int wid = tid >> 6;
  const int wr = wid >> 1, wc = wid & 1;
  const int quad = lane >> 4, l15 = lane & 15;
  floatx4 zf = {0.f, 0.f, 0.f, 0.f};
  floatx4 acc[4][4] = {{zf, zf, zf, zf}, {zf, zf, zf, zf},
                       {zf, zf, zf, zf}, {zf, zf, zf, zf}};
  for (int k0 = 0; k0 < 384; k0 += 64) {
#pragma unroll
    for (int i = 0; i < 4; ++i) {
      int chunk = tid + i * 256;
      int r = chunk >> 3, c8 = chunk & 7;
      int kcol = k0 + ((c8 ^ (r & 7)) * 8);
      async16(&A[(size_t)(mb + r) * 384 + kcol], &Al[((tid & 192) + i * 256) * 8]);
      async16(&W[(size_t)(nb + r) * 384 + kcol], &Bl[((tid & 192) + i * 256) * 8]);
    }
    __syncthreads();
    bhalf8 af[4][2], bf[4][2];
#pragma unroll
    for (int mi = 0; mi < 4; ++mi)
#pragma unroll
      for (int s = 0; s < 2; ++s) {
        int row = wr * 64 + mi * 16 + l15;
        af[mi][s] = *(const bhalf8*)&Al[row * 64 + (((s * 4 + quad) ^ (row & 7)) * 8)];
        int col = wc * 64 + mi * 16 + l15;
        bf[mi][s] = *(const bhalf8*)&Bl[col * 64 + (((s * 4 + quad) ^ (col & 7)) * 8)];
      }
#pragma unroll
    for (int mi = 0; mi < 4; ++mi)
#pragma unroll
      for (int ni = 0; ni < 4; ++ni) {
        acc[mi][ni] = MFMA16(af[mi][0], bf[ni][0], acc[mi][ni], 0, 0, 0);
        acc[mi][ni] = MFMA16(af[mi][1], bf[ni][1], acc[mi][ni], 0, 0, 0);
      }
    __syncthreads();
  }
  if (epi == 2) {
#pragma unroll
    for (int mi = 0; mi < 4; ++mi)
#pragma unroll
      for (int ni = 0; ni < 4; ++ni)
#pragma unroll
        for (int r = 0; r < 4; ++r) {
          int m = mb + wr * 64 + mi * 16 + quad * 4 + r;
          int n = nb + wc * 64 + ni * 16 + l15;
          dout[(size_t)m * 384 + n] = acc[mi][ni][r] + bias[n];
        }
  } else if (epi == 0) {
#pragma unroll
    for (int mi = 0; mi < 4; ++mi)
#pragma unroll
      for (int ni = 0; ni < 4; ++ni)
#pragma unroll
        for (int r = 0; r < 4; ++r) {
          int m = mb + wr * 64 + mi * 16 + quad * 4 + r;
          int n = nb + wc * 64 + ni * 16 + l15;
          int b = m / 784, t = m - b * 784;
          outb[(((size_t)b * 6 + (n >> 6)) * 784 + t) * 64 + (n & 63)] =
              f2bf(acc[mi][ni][r] * osc);
        }
  } else {
    // repack C -> Ct[n][m] (b64 packed along m), then coalesced b128 stores along t
#pragma unroll
    for (int mi = 0; mi < 4; ++mi)
#pragma unroll
      for (int ni = 0; ni < 4; ++ni) {
        int nl = wc * 64 + ni * 16 + l15;
        int ml = wr * 64 + mi * 16 + quad * 4;
        unsigned lo = ((unsigned)f2bf(acc[mi][ni][1]) << 16) | f2bf(acc[mi][ni][0]);
        unsigned hi = ((unsigned)f2bf(acc[mi][ni][3]) << 16) | f2bf(acc[mi][ni][2]);
        uint2 pk = {lo, hi};
        *(uint2*)&SB[nl * 136 + ml] = pk;
      }
    __syncthreads();
#pragma unroll
    for (int p = 0; p < 8; ++p) {
      int idx = tid + p * 256;
      int row = idx >> 4, ck = idx & 15;
      int m0 = mb + ck * 8;
      int b = m0 / 784, t0 = m0 - b * 784;   // 784 % 8 == 0: chunk never straddles b
      bhalf8 vv = *(const bhalf8*)&SB[row * 136 + ck * 8];
      __builtin_nontemporal_store(
          vv, (bhalf8*)&vht[(size_t)b * 301056 + (size_t)(nb + row) * 784 + t0]);
    }
  }
}

// -------- fused attention: P transposed in-register via permlane swaps, l via MFMA ----
// R5 exact shape (best measured: 49.5 us): 256 thr, KVBLK=64, 2x16KB dbuf, 0 conflicts,
// NO setprio (R9: -2 us -- no phase role-split in this structure, T5 regime absent).
__global__ __launch_bounds__(256, 4) void attn_kernel(
    const unsigned short* __restrict__ Q, const unsigned short* __restrict__ K,
    const unsigned short* __restrict__ Vt, unsigned short* __restrict__ O) {
  __shared__ __align__(16) unsigned short Kl[2][64 * 64];   // 16 KB
  __shared__ __align__(16) unsigned short Vl[2][64 * 64];   // 16 KB
  const int bh = blockIdx.x, qb = blockIdx.y * 128;
  const int tid = threadIdx.x, lane = tid & 63, wid = tid >> 6;
  const int quad = lane >> 4, l15 = lane & 15;
  const size_t hb = (size_t)bh * 50176;
  const unsigned short* Qh = Q + hb;
  const unsigned short* Kh = K + hb;
  const unsigned short* Vh = Vt + hb;  // [64][784]

  auto stage = [&](int kb2, int bufS) {
#pragma unroll
    for (int i = 0; i < 2; ++i) {
      int c = tid + i * 256;
      int tt = c >> 3, c8 = c & 7;
      int sw = (c8 ^ (tt & 7)) * 8;
      int row = kb2 + tt; if (row > 783) row = 783;
      async16(&Kh[(size_t)row * 64 + sw], &Kl[bufS][((tid & 192) + i * 256) * 8]);
      int col = kb2 + sw; if (col > 776) col = 776;
      async16(&Vh[(size_t)tt * 784 + col], &Vl[bufS][((tid & 192) + i * 256) * 8]);
    }
  };

  const int row0 = qb + wid * 32;           // wave's first q row
  const bool w0v = row0 < 784;              // wave has any valid rows (nt=0 tile)
  const bool w1v = (row0 + 16) < 784;       // nt=1 tile has valid rows

  bhalf8 zs = {0, 0, 0, 0, 0, 0, 0, 0};
  bhalf8 aq[2][2];  // Q as B-operand: lane n=q, k=d
#pragma unroll
  for (int nt = 0; nt < 2; ++nt) {
    int row = row0 + nt * 16 + l15;
#pragma unroll
    for (int d = 0; d < 2; ++d)
      aq[nt][d] = (row < 784) ? *(const bhalf8*)&Qh[(size_t)row * 64 + d * 32 + quad * 8]
                              : zs;
  }

  const bhalf8 ones = {16256, 16256, 16256, 16256, 16256, 16256, 16256, 16256};

  floatx4 zf = {0.f, 0.f, 0.f, 0.f};
  floatx4 accO[2][4] = {{zf, zf, zf, zf}, {zf, zf, zf, zf}};
  floatx4 accl[2] = {zf, zf};

  stage(0, 0);
  __syncthreads();

  for (int kt = 0; kt < 13; ++kt) {
    const int buf = kt & 1;
    const int kb = kt * 64;
    if (kt < 12) stage(kb + 64, buf ^ 1);

#pragma unroll
    for (int s = 0; s < 2; ++s) {
      if (kb + s * 32 >= 784) break;   // wave-uniform (last tile: only s=0 live)
      if (!w0v) continue;              // wave-uniform: no valid q rows -> skip compute
      const bool tok1 = (kb + s * 32 + 16) < 784;  // wave-uniform
      bhalf8 kk[2][2], vvs[4];
#pragma unroll
      for (int h = 0; h < 2; ++h)
#pragma unroll
        for (int d = 0; d < 2; ++d) {
          int tr = (2 * s + h) * 16 + l15;
          kk[h][d] = *(const bhalf8*)&Kl[buf][tr * 64 + (((d * 4 + quad) ^ (tr & 7)) * 8)];
        }
#pragma unroll
      for (int dt = 0; dt < 4; ++dt) {
        int dr = dt * 16 + l15;
        vvs[dt] = *(const bhalf8*)&Vl[buf][dr * 64 + (((s * 4 + quad) ^ (dr & 7)) * 8)];
      }
#pragma unroll
      for (int nt = 0; nt < 2; ++nt) {
        if (nt == 1 && !w1v) break;    // wave-uniform: nt=1 tile fully dead
        uint2 pk0 = {0u, 0u}, pk1 = {0u, 0u};
        {
          floatx4 sf = zf;
          sf = MFMA16(kk[0][0], aq[nt][0], sf, 0, 0, 0);
          sf = MFMA16(kk[0][1], aq[nt][1], sf, 0, 0, 0);
          pk0.x = __builtin_amdgcn_perm(fbits(__builtin_amdgcn_exp2f(sf[1])),
                                        fbits(__builtin_amdgcn_exp2f(sf[0])),
                                        0x07060302u);
          pk0.y = __builtin_amdgcn_perm(fbits(__builtin_amdgcn_exp2f(sf[3])),
                                        fbits(__builtin_amdgcn_exp2f(sf[2])),
                                        0x07060302u);
        }
        if (tok1) {
          floatx4 sf = zf;
          sf = MFMA16(kk[1][0], aq[nt][0], sf, 0, 0, 0);
          sf = MFMA16(kk[1][1], aq[nt][1], sf, 0, 0, 0);
          pk1.x = __builtin_amdgcn_perm(fbits(__builtin_amdgcn_exp2f(sf[1])),
                                        fbits(__builtin_amdgcn_exp2f(sf[0])),
                                        0x07060302u);
          pk1.y = __builtin_amdgcn_perm(fbits(__builtin_amdgcn_exp2f(sf[3])),
                                        fbits(__builtin_amdgcn_exp2f(sf[2])),
                                        0x07060302u);
        }
        // transpose P^T (C-layout) -> P (B-operand) fully in-register:
        //  t = permlane32_swap(a,b): t0={a.lo,b.lo}, t1={a.hi,b.hi}
        //  f = permlane16_swap(t0,t1): f0 rows={a.r0,a.r2,b.r0,b.r2},
        //                              f1 rows={a.r1,a.r3,b.r1,b.r3}
        auto sw0 = __builtin_amdgcn_permlane32_swap((int)pk0.x, (int)pk1.x, false, false);
        auto sw1 = __builtin_amdgcn_permlane32_swap((int)pk0.y, (int)pk1.y, false, false);
        auto f0 = __builtin_amdgcn_permlane16_swap(sw0[0], sw0[1], false, false);
        auto f1 = __builtin_amdgcn_permlane16_swap(sw1[0], sw1[1], false, false);
        union { uint4 u; bhalf8 v; } pf;
        pf.u.x = (unsigned)f0[0];
        pf.u.y = (unsigned)f1[0];
        pf.u.z = (unsigned)f0[1];
        pf.u.w = (unsigned)f1[1];
        accl[nt] = MFMA16(ones, pf.v, accl[nt], 0, 0, 0);
#pragma unroll
        for (int dt = 0; dt < 4; ++dt)
          accO[nt][dt] = MFMA16(vvs[dt], pf.v, accO[nt][dt], 0, 0, 0);
      }
    }
    __syncthreads();
  }

  const int b = bh / 6, h = bh - b * 6;
#pragma unroll
  for (int nt = 0; nt < 2; ++nt) {
    float iv = 1.f / accl[nt][0];
    int q = qb + wid * 32 + nt * 16 + l15;
    if (q < 784) {
#pragma unroll
      for (int dt = 0; dt < 4; ++dt) {
        us4 o;
        o.x = f2bf(accO[nt][dt][0] * iv);
        o.y = f2bf(accO[nt][dt][1] * iv);
        o.z = f2bf(accO[nt][dt][2] * iv);
        o.w = f2bf(accO[nt][dt][3] * iv);
        *(us4*)&O[((size_t)b * 784 + q) * 384 + h * 64 + dt * 16 + quad * 4] = o;
      }
    }
  }
}

extern "C" void kernel_launch(void* const* d_in, const int* in_sizes, int n_in,
                              void* d_out, int out_size, void* d_ws, size_t ws_size,
                              hipStream_t stream) {
  const float* x   = (const float*)d_in[0];
  const float* cwq = (const float*)d_in[3];
  const float* gq  = (const float*)d_in[4];
  const float* bq  = (const float*)d_in[5];
  const float* mq  = (const float*)d_in[6];
  const float* vq  = (const float*)d_in[7];
  const float* cwk = (const float*)d_in[8];
  const float* gk  = (const float*)d_in[9];
  const float* bk  = (const float*)d_in[10];
  const float* mk  = (const float*)d_in[11];
  const float* vk  = (const float*)d_in[12];
  const float* cwv = (const float*)d_in[13];
  const float* gv  = (const float*)d_in[14];
  const float* bv  = (const float*)d_in[15];
  const float* mv  = (const float*)d_in[16];
  const float* vv  = (const float*)d_in[17];
  const float* wq  = (const float*)d_in[18];
  const float* wk  = (const float*)d_in[19];
  const float* wv  = (const float*)d_in[20];
  const float* wp  = (const float*)d_in[21];
  const float* bp  = (const float*)d_in[22];

  unsigned short* ws = (unsigned short*)d_ws;
  const size_t SZ = (size_t)25088 * 384;
  unsigned short* qt  = ws;             // [25088,384] bf16; reused as attn out
  unsigned short* ktt = ws + SZ;
  unsigned short* vtt = ws + 2 * SZ;
  unsigned short* qh  = ws + 3 * SZ;    // [192][784][64]
  unsigned short* kh  = ws + 4 * SZ;
  unsigned short* vht = ws + 5 * SZ;    // [192][64][784]
  unsigned short* wbf = ws + 6 * SZ;    // 4 x [384,384] bf16
  float* fx = (float*)(ws + 5 * SZ);    // aliases vht: fx dead before vht written
  unsigned short* ob = qt;

  cvtw_prep_kernel<<<dim3(577), dim3(256), 0, stream>>>(
      wq, wk, wv, wp, wbf,
      cwq, gq, bq, mq, vq, cwk, gk, bk, mk, vk, cwv, gv, bv, mv, vv, fx);
  dwconv_bn_kernel<<<dim3(1568), dim3(384), 0, stream>>>(x, fx, qt, ktt, vtt);
  gemm128_kernel<<<dim3(3, 196, 3), dim3(256), 0, stream>>>(
      qt, ktt, vtt, wbf, bp, qh, kh, vht, (float*)d_out, 0);
  attn_kernel<<<dim3(192, 7), dim3(256), 0, stream>>>(qh, kh, vht, ob);
  gemm128_kernel<<<dim3(3, 196, 1), dim3(256), 0, stream>>>(
      ob, ktt, vtt, wbf, bp, qh, kh, vht, (float*)d_out, 1);
}

// Round 12
// 254.457 us; speedup vs baseline: 1.0886x; 1.0886x over previous
//
#include <hip/hip_runtime.h>

typedef __attribute__((ext_vector_type(8))) short bhalf8;
typedef __attribute__((ext_vector_type(4))) float floatx4;

#define MFMA16 __builtin_amdgcn_mfma_f32_16x16x32_bf16
#define SCALE_EXP2 0.07362225f          // 384^-0.5 * log2(e), folded into Q

__device__ __forceinline__ unsigned short f2bf(float f) {
  union { float fl; unsigned u; } v;
  v.fl = f;
  unsigned r = v.u + 0x7fffu + ((v.u >> 16) & 1u);
  return (unsigned short)(r >> 16);
}
__device__ __forceinline__ unsigned fbits(float f) {
  union { float fl; unsigned u; } v; v.fl = f; return v.u;
}

typedef const __attribute__((address_space(1))) unsigned int* gas1_t;
typedef __attribute__((address_space(3))) unsigned int* las3_t;
// async global->LDS, 16 B per lane; LDS dest = wave-uniform base + lane*16
__device__ __forceinline__ void async16(const void* g, void* l) {
  __builtin_amdgcn_global_load_lds((gas1_t)g, (las3_t)l, 16, 0, 0);
}

struct __align__(8) us4 { unsigned short x, y, z, w; };

// ---------------- weights fp32->bf16 + conv-weight transpose/BN-fold ----------------
// fx layout (floats): per-cv contiguous block of 4224 floats (1056 float4):
//   [cv*4224 + i*384 + c]  i<9  : transposed conv taps
//   [cv*4224 + 3456 + c]         : inv scale
//   [cv*4224 + 3840 + c]         : shift
__global__ __launch_bounds__(256) void cvtw_prep_kernel(
    const float* __restrict__ wq, const float* __restrict__ wk,
    const float* __restrict__ wv, const float* __restrict__ wp,
    unsigned short* __restrict__ o,
    const float* __restrict__ cwq, const float* __restrict__ gq,
    const float* __restrict__ bq,  const float* __restrict__ mq,
    const float* __restrict__ vq,
    const float* __restrict__ cwk, const float* __restrict__ gk,
    const float* __restrict__ bk,  const float* __restrict__ mk,
    const float* __restrict__ vk,
    const float* __restrict__ cwv, const float* __restrict__ gv,
    const float* __restrict__ bv,  const float* __restrict__ mv,
    const float* __restrict__ vv,
    float* __restrict__ fx) {
  if (blockIdx.x < 576) {
    int i = blockIdx.x * 256 + threadIdx.x;
    o[i]          = f2bf(wq[i]);
    o[147456 + i] = f2bf(wk[i]);
    o[294912 + i] = f2bf(wv[i]);
    o[442368 + i] = f2bf(wp[i]);
    return;
  }
  const float* cw[3] = {cwq, cwk, cwv};
  const float* gg[3] = {gq, gk, gv};
  const float* bb[3] = {bq, bk, bv};
  const float* mm[3] = {mq, mk, mv};
  const float* vr[3] = {vq, vk, vv};
  for (int c = threadIdx.x; c < 384; c += 256) {
#pragma unroll
    for (int cv = 0; cv < 3; ++cv) {
#pragma unroll
      for (int i = 0; i < 9; ++i) fx[cv * 4224 + i * 384 + c] = cw[cv][c * 9 + i];
      float inv = gg[cv][c] * rsqrtf(vr[cv][c] + 1e-5f);
      fx[cv * 4224 + 3456 + c] = inv;
      fx[cv * 4224 + 3840 + c] = bb[cv][c] - mm[cv][c] * inv;
    }
  }
}

// ---- depthwise 3x3 conv + BN; 4 output rows/thread, taps loaded once, 18-deep MLP ----
// Plain stores: outputs are consumed by the next kernel and the ~115 MB intermediate
// footprint fits L3 -- nt stores (R11) bypassed L3 and slowed the CONSUMERS by ~23 us.
__global__ __launch_bounds__(384) void dwconv_bn_kernel(
    const float* __restrict__ x, const float* __restrict__ fx,
    unsigned short* __restrict__ qt, unsigned short* __restrict__ kt,
    unsigned short* __restrict__ vt) {
  __shared__ __align__(16) float4 Wl[3168];   // 50688 B, fx image
  const int tid = threadIdx.x;
  const int tok = tid / 96;
  const int g   = tid - tok * 96;
  int blk = blockIdx.x;                  // b*49 + yp*7 + xg
  int b   = blk / 49;
  int rr  = blk - b * 49;
  int yp  = rr / 7;
  int xg  = rr - yp * 7;
  int y0  = yp * 4;
  int xx  = xg * 4 + tok;
  const float4* xv = (const float4*)x;
  float4 z4 = {0.f, 0.f, 0.f, 0.f};
  float4 tap[6][3];                      // rows y0-1..y0+4, cols xx-1..xx+1
#pragma unroll
  for (int dy = 0; dy < 6; ++dy)
#pragma unroll
    for (int dx = 0; dx < 3; ++dx) {
      int yy = y0 - 1 + dy, xc = xx - 1 + dx;
      bool ok = ((unsigned)yy < 28u) & ((unsigned)xc < 28u);
      tap[dy][dx] = ok ? xv[((size_t)b * 784 + yy * 28 + xc) * 96 + g] : z4;
    }
  const float4* fxv = (const float4*)fx;
  for (int i = tid; i < 3168; i += 384) Wl[i] = fxv[i];
  __syncthreads();
  floatx4 acc[3][4];
#pragma unroll
  for (int cv = 0; cv < 3; ++cv)
#pragma unroll
    for (int j = 0; j < 4; ++j) acc[cv][j] = (floatx4){0.f, 0.f, 0.f, 0.f};
#pragma unroll
  for (int i = 0; i < 9; ++i) {
    int dy = i / 3, dx = i - dy * 3;
    float4 w0 = Wl[i * 96 + g];
    float4 w1 = Wl[1056 + i * 96 + g];
    float4 w2 = Wl[2112 + i * 96 + g];
#pragma unroll
    for (int j = 0; j < 4; ++j) {
      float4 t = tap[j + dy][dx];
      acc[0][j][0] += t.x * w0.x; acc[0][j][1] += t.y * w0.y;
      acc[0][j][2] += t.z * w0.z; acc[0][j][3] += t.w * w0.w;
      acc[1][j][0] += t.x * w1.x; acc[1][j][1] += t.y * w1.y;
      acc[1][j][2] += t.z * w1.z; acc[1][j][3] += t.w * w1.w;
      acc[2][j][0] += t.x * w2.x; acc[2][j][1] += t.y * w2.y;
      acc[2][j][2] += t.z * w2.z; acc[2][j][3] += t.w * w2.w;
    }
  }
  unsigned short* outs[3] = {qt, kt, vt};
  size_t o0 = ((size_t)b * 784 + y0 * 28 + xx) * 96 + g;   // us4 units
#pragma unroll
  for (int cv = 0; cv < 3; ++cv) {
    float4 inv = Wl[cv * 1056 + 864 + g];
    float4 sh  = Wl[cv * 1056 + 960 + g];
#pragma unroll
    for (int j = 0; j < 4; ++j) {
      us4 o;
      o.x = f2bf(acc[cv][j][0] * inv.x + sh.x);
      o.y = f2bf(acc[cv][j][1] * inv.y + sh.y);
      o.z = f2bf(acc[cv][j][2] * inv.z + sh.z);
      o.w = f2bf(acc[cv][j][3] * inv.w + sh.w);
      ((us4*)outs[cv])[o0 + (size_t)j * 28 * 96] = o;
    }
  }
}

// ---------------- 128x128 GEMM, merged QKV (mode 0, z-dispatch) / proj (mode 1) ------
// blockIdx (x,y) remapped XCD-chunked so the 3 nb-blocks sharing an A row-panel land
// on the same XCD's L2. Bijective for ANY z-phase: chunk capacity of each actual XCD
// equals the exact count of blocks landing there (prefix-sum over per-residue counts).
__global__ __launch_bounds__(256) void gemm128_kernel(
    const unsigned short* __restrict__ A0, const unsigned short* __restrict__ A1,
    const unsigned short* __restrict__ A2, const unsigned short* __restrict__ wbf,
    const float* __restrict__ bias,
    unsigned short* __restrict__ qh, unsigned short* __restrict__ kh,
    unsigned short* __restrict__ vht, float* __restrict__ dout, int mode) {
  __shared__ __align__(16) unsigned short SB[17408];  // Al | Bl ; reused as Ct[128][136]
  unsigned short* Al = SB;
  unsigned short* Bl = SB + 8192;
  const unsigned short* A;
  const unsigned short* W;
  int epi;
  float osc = 1.f;
  unsigned short* outb = nullptr;
  if (mode == 0) {
    int z = blockIdx.z;
    A = (z == 0) ? A0 : ((z == 1) ? A1 : A2);
    W = wbf + z * 147456;
    epi = (z == 2) ? 1 : 0;
    outb = (z == 0) ? qh : ((z == 1) ? kh : vht);
    if (z == 0) osc = SCALE_EXP2;        // fold softmax scale+log2e into Q
  } else {
    A = A0; W = wbf + 442368; epi = 2;
  }
  // bijective XCD-chunked remap of the (x,y) block space
  const int nwg  = gridDim.x * gridDim.y;
  const int orig = blockIdx.y * gridDim.x + blockIdx.x;
  const int qq = nwg >> 3, rr8 = nwg & 7;
  const int sft = (int)((unsigned)(blockIdx.z * nwg) & 7u);  // z-phase of linear id
  const int xcd = (orig + sft) & 7;                          // actual XCD of this block
  int base = 0;
  for (int c = 0; c < xcd; ++c) base += qq + ((((c - sft) & 7) < rr8) ? 1 : 0);
  const int nid = base + (orig >> 3);
  const int nb = (nid % gridDim.x) * 128, mb = (nid / gridDim.x) * 128;
  const int tid = threadIdx.x, lane = tid & 63;
  const int wid = tid >> 6;
  const int wr = wid >> 1, wc = wid & 1;
  const int quad = lane >> 4, l15 = lane & 15;
  floatx4 zf = {0.f, 0.f, 0.f, 0.f};
  floatx4 acc[4][4] = {{zf, zf, zf, zf}, {zf, zf, zf, zf},
                       {zf, zf, zf, zf}, {zf, zf, zf, zf}};
  for (int k0 = 0; k0 < 384; k0 += 64) {
#pragma unroll
    for (int i = 0; i < 4; ++i) {
      int chunk = tid + i * 256;
      int r = chunk >> 3, c8 = chunk & 7;
      int kcol = k0 + ((c8 ^ (r & 7)) * 8);
      async16(&A[(size_t)(mb + r) * 384 + kcol], &Al[((tid & 192) + i * 256) * 8]);
      async16(&W[(size_t)(nb + r) * 384 + kcol], &Bl[((tid & 192) + i * 256) * 8]);
    }
    __syncthreads();
    bhalf8 af[4][2], bf[4][2];
#pragma unroll
    for (int mi = 0; mi < 4; ++mi)
#pragma unroll
      for (int s = 0; s < 2; ++s) {
        int row = wr * 64 + mi * 16 + l15;
        af[mi][s] = *(const bhalf8*)&Al[row * 64 + (((s * 4 + quad) ^ (row & 7)) * 8)];
        int col = wc * 64 + mi * 16 + l15;
        bf[mi][s] = *(const bhalf8*)&Bl[col * 64 + (((s * 4 + quad) ^ (col & 7)) * 8)];
      }
#pragma unroll
    for (int mi = 0; mi < 4; ++mi)
#pragma unroll
      for (int ni = 0; ni < 4; ++ni) {
        acc[mi][ni] = MFMA16(af[mi][0], bf[ni][0], acc[mi][ni], 0, 0, 0);
        acc[mi][ni] = MFMA16(af[mi][1], bf[ni][1], acc[mi][ni], 0, 0, 0);
      }
    __syncthreads();
  }
  if (epi == 2) {
#pragma unroll
    for (int mi = 0; mi < 4; ++mi)
#pragma unroll
      for (int ni = 0; ni < 4; ++ni)
#pragma unroll
        for (int r = 0; r < 4; ++r) {
          int m = mb + wr * 64 + mi * 16 + quad * 4 + r;
          int n = nb + wc * 64 + ni * 16 + l15;
          dout[(size_t)m * 384 + n] = acc[mi][ni][r] + bias[n];
        }
  } else if (epi == 0) {
#pragma unroll
    for (int mi = 0; mi < 4; ++mi)
#pragma unroll
      for (int ni = 0; ni < 4; ++ni)
#pragma unroll
        for (int r = 0; r < 4; ++r) {
          int m = mb + wr * 64 + mi * 16 + quad * 4 + r;
          int n = nb + wc * 64 + ni * 16 + l15;
          int b = m / 784, t = m - b * 784;
          outb[(((size_t)b * 6 + (n >> 6)) * 784 + t) * 64 + (n & 63)] =
              f2bf(acc[mi][ni][r] * osc);
        }
  } else {
    // repack C -> Ct[n][m] (b64 packed along m), then coalesced b128 stores along t
#pragma unroll
    for (int mi = 0; mi < 4; ++mi)
#pragma unroll
      for (int ni = 0; ni < 4; ++ni) {
        int nl = wc * 64 + ni * 16 + l15;
        int ml = wr * 64 + mi * 16 + quad * 4;
        unsigned lo = ((unsigned)f2bf(acc[mi][ni][1]) << 16) | f2bf(acc[mi][ni][0]);
        unsigned hi = ((unsigned)f2bf(acc[mi][ni][3]) << 16) | f2bf(acc[mi][ni][2]);
        uint2 pk = {lo, hi};
        *(uint2*)&SB[nl * 136 + ml] = pk;
      }
    __syncthreads();
#pragma unroll
    for (int p = 0; p < 8; ++p) {
      int idx = tid + p * 256;
      int row = idx >> 4, ck = idx & 15;
      int m0 = mb + ck * 8;
      int b = m0 / 784, t0 = m0 - b * 784;   // 784 % 8 == 0: chunk never straddles b
      bhalf8 vv = *(const bhalf8*)&SB[row * 136 + ck * 8];
      *(bhalf8*)&vht[(size_t)b * 301056 + (size_t)(nb + row) * 784 + t0] = vv;
    }
  }
}

// -------- fused attention: P transposed in-register via permlane swaps, l via MFMA ----
// R5 exact shape (best measured: 49.5 us): 256 thr, KVBLK=64, 2x16KB dbuf, 0 conflicts,
// NO setprio (R9: -2 us -- no phase role-split in this structure, T5 regime absent).
__global__ __launch_bounds__(256, 4) void attn_kernel(
    const unsigned short* __restrict__ Q, const unsigned short* __restrict__ K,
    const unsigned short* __restrict__ Vt, unsigned short* __restrict__ O) {
  __shared__ __align__(16) unsigned short Kl[2][64 * 64];   // 16 KB
  __shared__ __align__(16) unsigned short Vl[2][64 * 64];   // 16 KB
  const int bh = blockIdx.x, qb = blockIdx.y * 128;
  const int tid = threadIdx.x, lane = tid & 63, wid = tid >> 6;
  const int quad = lane >> 4, l15 = lane & 15;
  const size_t hb = (size_t)bh * 50176;
  const unsigned short* Qh = Q + hb;
  const unsigned short* Kh = K + hb;
  const unsigned short* Vh = Vt + hb;  // [64][784]

  auto stage = [&](int kb2, int bufS) {
#pragma unroll
    for (int i = 0; i < 2; ++i) {
      int c = tid + i * 256;
      int tt = c >> 3, c8 = c & 7;
      int sw = (c8 ^ (tt & 7)) * 8;
      int row = kb2 + tt; if (row > 783) row = 783;
      async16(&Kh[(size_t)row * 64 + sw], &Kl[bufS][((tid & 192) + i * 256) * 8]);
      int col = kb2 + sw; if (col > 776) col = 776;
      async16(&Vh[(size_t)tt * 784 + col], &Vl[bufS][((tid & 192) + i * 256) * 8]);
    }
  };

  const int row0 = qb + wid * 32;           // wave's first q row
  const bool w0v = row0 < 784;              // wave has any valid rows (nt=0 tile)
  const bool w1v = (row0 + 16) < 784;       // nt=1 tile has valid rows

  bhalf8 zs = {0, 0, 0, 0, 0, 0, 0, 0};
  bhalf8 aq[2][2];  // Q as B-operand: lane n=q, k=d
#pragma unroll
  for (int nt = 0; nt < 2; ++nt) {
    int row = row0 + nt * 16 + l15;
#pragma unroll
    for (int d = 0; d < 2; ++d)
      aq[nt][d] = (row < 784) ? *(const bhalf8*)&Qh[(size_t)row * 64 + d * 32 + quad * 8]
                              : zs;
  }

  const bhalf8 ones = {16256, 16256, 16256, 16256, 16256, 16256, 16256, 16256};

  floatx4 zf = {0.f, 0.f, 0.f, 0.f};
  floatx4 accO[2][4] = {{zf, zf, zf, zf}, {zf, zf, zf, zf}};
  floatx4 accl[2] = {zf, zf};

  stage(0, 0);
  __syncthreads();

  for (int kt = 0; kt < 13; ++kt) {
    const int buf = kt & 1;
    const int kb = kt * 64;
    if (kt < 12) stage(kb + 64, buf ^ 1);

#pragma unroll
    for (int s = 0; s < 2; ++s) {
      if (kb + s * 32 >= 784) break;   // wave-uniform (last tile: only s=0 live)
      if (!w0v) continue;              // wave-uniform: no valid q rows -> skip compute
      const bool tok1 = (kb + s * 32 + 16) < 784;  // wave-uniform
      bhalf8 kk[2][2], vvs[4];
#pragma unroll
      for (int h = 0; h < 2; ++h)
#pragma unroll
        for (int d = 0; d < 2; ++d) {
          int tr = (2 * s + h) * 16 + l15;
          kk[h][d] = *(const bhalf8*)&Kl[buf][tr * 64 + (((d * 4 + quad) ^ (tr & 7)) * 8)];
        }
#pragma unroll
      for (int dt = 0; dt < 4; ++dt) {
        int dr = dt * 16 + l15;
        vvs[dt] = *(const bhalf8*)&Vl[buf][dr * 64 + (((s * 4 + quad) ^ (dr & 7)) * 8)];
      }
#pragma unroll
      for (int nt = 0; nt < 2; ++nt) {
        if (nt == 1 && !w1v) break;    // wave-uniform: nt=1 tile fully dead
        uint2 pk0 = {0u, 0u}, pk1 = {0u, 0u};
        {
          floatx4 sf = zf;
          sf = MFMA16(kk[0][0], aq[nt][0], sf, 0, 0, 0);
          sf = MFMA16(kk[0][1], aq[nt][1], sf, 0, 0, 0);
          pk0.x = __builtin_amdgcn_perm(fbits(__builtin_amdgcn_exp2f(sf[1])),
                                        fbits(__builtin_amdgcn_exp2f(sf[0])),
                                        0x07060302u);
          pk0.y = __builtin_amdgcn_perm(fbits(__builtin_amdgcn_exp2f(sf[3])),
                                        fbits(__builtin_amdgcn_exp2f(sf[2])),
                                        0x07060302u);
        }
        if (tok1) {
          floatx4 sf = zf;
          sf = MFMA16(kk[1][0], aq[nt][0], sf, 0, 0, 0);
          sf = MFMA16(kk[1][1], aq[nt][1], sf, 0, 0, 0);
          pk1.x = __builtin_amdgcn_perm(fbits(__builtin_amdgcn_exp2f(sf[1])),
                                        fbits(__builtin_amdgcn_exp2f(sf[0])),
                                        0x07060302u);
          pk1.y = __builtin_amdgcn_perm(fbits(__builtin_amdgcn_exp2f(sf[3])),
                                        fbits(__builtin_amdgcn_exp2f(sf[2])),
                                        0x07060302u);
        }
        // transpose P^T (C-layout) -> P (B-operand) fully in-register:
        //  t = permlane32_swap(a,b): t0={a.lo,b.lo}, t1={a.hi,b.hi}
        //  f = permlane16_swap(t0,t1): f0 rows={a.r0,a.r2,b.r0,b.r2},
        //                              f1 rows={a.r1,a.r3,b.r1,b.r3}
        auto sw0 = __builtin_amdgcn_permlane32_swap((int)pk0.x, (int)pk1.x, false, false);
        auto sw1 = __builtin_amdgcn_permlane32_swap((int)pk0.y, (int)pk1.y, false, false);
        auto f0 = __builtin_amdgcn_permlane16_swap(sw0[0], sw0[1], false, false);
        auto f1 = __builtin_amdgcn_permlane16_swap(sw1[0], sw1[1], false, false);
        union { uint4 u; bhalf8 v; } pf;
        pf.u.x = (unsigned)f0[0];
        pf.u.y = (unsigned)f1[0];
        pf.u.z = (unsigned)f0[1];
        pf.u.w = (unsigned)f1[1];
        accl[nt] = MFMA16(ones, pf.v, accl[nt], 0, 0, 0);
#pragma unroll
        for (int dt = 0; dt < 4; ++dt)
          accO[nt][dt] = MFMA16(vvs[dt], pf.v, accO[nt][dt], 0, 0, 0);
      }
    }
    __syncthreads();
  }

  const int b = bh / 6, h = bh - b * 6;
#pragma unroll
  for (int nt = 0; nt < 2; ++nt) {
    float iv = 1.f / accl[nt][0];
    int q = qb + wid * 32 + nt * 16 + l15;
    if (q < 784) {
#pragma unroll
      for (int dt = 0; dt < 4; ++dt) {
        us4 o;
        o.x = f2bf(accO[nt][dt][0] * iv);
        o.y = f2bf(accO[nt][dt][1] * iv);
        o.z = f2bf(accO[nt][dt][2] * iv);
        o.w = f2bf(accO[nt][dt][3] * iv);
        *(us4*)&O[((size_t)b * 784 + q) * 384 + h * 64 + dt * 16 + quad * 4] = o;
      }
    }
  }
}

extern "C" void kernel_launch(void* const* d_in, const int* in_sizes, int n_in,
                              void* d_out, int out_size, void* d_ws, size_t ws_size,
                              hipStream_t stream) {
  const float* x   = (const float*)d_in[0];
  const float* cwq = (const float*)d_in[3];
  const float* gq  = (const float*)d_in[4];
  const float* bq  = (const float*)d_in[5];
  const float* mq  = (const float*)d_in[6];
  const float* vq  = (const float*)d_in[7];
  const float* cwk = (const float*)d_in[8];
  const float* gk  = (const float*)d_in[9];
  const float* bk  = (const float*)d_in[10];
  const float* mk  = (const float*)d_in[11];
  const float* vk  = (const float*)d_in[12];
  const float* cwv = (const float*)d_in[13];
  const float* gv  = (const float*)d_in[14];
  const float* bv  = (const float*)d_in[15];
  const float* mv  = (const float*)d_in[16];
  const float* vv  = (const float*)d_in[17];
  const float* wq  = (const float*)d_in[18];
  const float* wk  = (const float*)d_in[19];
  const float* wv  = (const float*)d_in[20];
  const float* wp  = (const float*)d_in[21];
  const float* bp  = (const float*)d_in[22];

  unsigned short* ws = (unsigned short*)d_ws;
  const size_t SZ = (size_t)25088 * 384;
  unsigned short* qt  = ws;             // [25088,384] bf16; reused as attn out
  unsigned short* ktt = ws + SZ;
  unsigned short* vtt = ws + 2 * SZ;
  unsigned short* qh  = ws + 3 * SZ;    // [192][784][64]
  unsigned short* kh  = ws + 4 * SZ;
  unsigned short* vht = ws + 5 * SZ;    // [192][64][784]
  unsigned short* wbf = ws + 6 * SZ;    // 4 x [384,384] bf16
  float* fx = (float*)(ws + 5 * SZ);    // aliases vht: fx dead before vht written
  unsigned short* ob = qt;

  cvtw_prep_kernel<<<dim3(577), dim3(256), 0, stream>>>(
      wq, wk, wv, wp, wbf,
      cwq, gq, bq, mq, vq, cwk, gk, bk, mk, vk, cwv, gv, bv, mv, vv, fx);
  dwconv_bn_kernel<<<dim3(1568), dim3(384), 0, stream>>>(x, fx, qt, ktt, vtt);
  gemm128_kernel<<<dim3(3, 196, 3), dim3(256), 0, stream>>>(
      qt, ktt, vtt, wbf, bp, qh, kh, vht, (float*)d_out, 0);
  attn_kernel<<<dim3(192, 7), dim3(256), 0, stream>>>(qh, kh, vht, ob);
  gemm128_kernel<<<dim3(3, 196, 1), dim3(256), 0, stream>>>(
      ob, ktt, vtt, wbf, bp, qh, kh, vht, (float*)d_out, 1);
}

// Round 13
// 253.135 us; speedup vs baseline: 1.0943x; 1.0052x over previous
//
#include <hip/hip_runtime.h>

typedef __attribute__((ext_vector_type(8))) short bhalf8;
typedef __attribute__((ext_vector_type(4))) float floatx4;

#define MFMA16 __builtin_amdgcn_mfma_f32_16x16x32_bf16
#define SCALE_EXP2 0.07362225f          // 384^-0.5 * log2(e), folded into Q

__device__ __forceinline__ unsigned short f2bf(float f) {
  union { float fl; unsigned u; } v;
  v.fl = f;
  unsigned r = v.u + 0x7fffu + ((v.u >> 16) & 1u);
  return (unsigned short)(r >> 16);
}
__device__ __forceinline__ unsigned fbits(float f) {
  union { float fl; unsigned u; } v; v.fl = f; return v.u;
}

typedef const __attribute__((address_space(1))) unsigned int* gas1_t;
typedef __attribute__((address_space(3))) unsigned int* las3_t;
// async global->LDS, 16 B per lane; LDS dest = wave-uniform base + lane*16
__device__ __forceinline__ void async16(const void* g, void* l) {
  __builtin_amdgcn_global_load_lds((gas1_t)g, (las3_t)l, 16, 0, 0);
}

struct __align__(8) us4 { unsigned short x, y, z, w; };

// ---------------- weights fp32->bf16 + conv-weight transpose/BN-fold ----------------
// fx layout (floats): per-cv contiguous block of 4224 floats (1056 float4):
//   [cv*4224 + i*384 + c]  i<9  : transposed conv taps
//   [cv*4224 + 3456 + c]         : inv scale
//   [cv*4224 + 3840 + c]         : shift
__global__ __launch_bounds__(256) void cvtw_prep_kernel(
    const float* __restrict__ wq, const float* __restrict__ wk,
    const float* __restrict__ wv, const float* __restrict__ wp,
    unsigned short* __restrict__ o,
    const float* __restrict__ cwq, const float* __restrict__ gq,
    const float* __restrict__ bq,  const float* __restrict__ mq,
    const float* __restrict__ vq,
    const float* __restrict__ cwk, const float* __restrict__ gk,
    const float* __restrict__ bk,  const float* __restrict__ mk,
    const float* __restrict__ vk,
    const float* __restrict__ cwv, const float* __restrict__ gv,
    const float* __restrict__ bv,  const float* __restrict__ mv,
    const float* __restrict__ vv,
    float* __restrict__ fx) {
  if (blockIdx.x < 576) {
    int i = blockIdx.x * 256 + threadIdx.x;
    o[i]          = f2bf(wq[i]);
    o[147456 + i] = f2bf(wk[i]);
    o[294912 + i] = f2bf(wv[i]);
    o[442368 + i] = f2bf(wp[i]);
    return;
  }
  const float* cw[3] = {cwq, cwk, cwv};
  const float* gg[3] = {gq, gk, gv};
  const float* bb[3] = {bq, bk, bv};
  const float* mm[3] = {mq, mk, mv};
  const float* vr[3] = {vq, vk, vv};
  for (int c = threadIdx.x; c < 384; c += 256) {
#pragma unroll
    for (int cv = 0; cv < 3; ++cv) {
#pragma unroll
      for (int i = 0; i < 9; ++i) fx[cv * 4224 + i * 384 + c] = cw[cv][c * 9 + i];
      float inv = gg[cv][c] * rsqrtf(vr[cv][c] + 1e-5f);
      fx[cv * 4224 + 3456 + c] = inv;
      fx[cv * 4224 + 3840 + c] = bb[cv][c] - mm[cv][c] * inv;
    }
  }
}

// ---- depthwise 3x3 conv + BN; 4 output rows/thread, taps loaded once, 18-deep MLP ----
// Plain stores: outputs are consumed by the next kernel and the ~115 MB intermediate
// footprint fits L3 -- nt stores (R11) bypassed L3 and slowed the CONSUMERS by ~23 us.
__global__ __launch_bounds__(384) void dwconv_bn_kernel(
    const float* __restrict__ x, const float* __restrict__ fx,
    unsigned short* __restrict__ qt, unsigned short* __restrict__ kt,
    unsigned short* __restrict__ vt) {
  __shared__ __align__(16) float4 Wl[3168];   // 50688 B, fx image
  const int tid = threadIdx.x;
  const int tok = tid / 96;
  const int g   = tid - tok * 96;
  int blk = blockIdx.x;                  // b*49 + yp*7 + xg
  int b   = blk / 49;
  int rr  = blk - b * 49;
  int yp  = rr / 7;
  int xg  = rr - yp * 7;
  int y0  = yp * 4;
  int xx  = xg * 4 + tok;
  const float4* xv = (const float4*)x;
  float4 z4 = {0.f, 0.f, 0.f, 0.f};
  float4 tap[6][3];                      // rows y0-1..y0+4, cols xx-1..xx+1
#pragma unroll
  for (int dy = 0; dy < 6; ++dy)
#pragma unroll
    for (int dx = 0; dx < 3; ++dx) {
      int yy = y0 - 1 + dy, xc = xx - 1 + dx;
      bool ok = ((unsigned)yy < 28u) & ((unsigned)xc < 28u);
      tap[dy][dx] = ok ? xv[((size_t)b * 784 + yy * 28 + xc) * 96 + g] : z4;
    }
  const float4* fxv = (const float4*)fx;
  for (int i = tid; i < 3168; i += 384) Wl[i] = fxv[i];
  __syncthreads();
  floatx4 acc[3][4];
#pragma unroll
  for (int cv = 0; cv < 3; ++cv)
#pragma unroll
    for (int j = 0; j < 4; ++j) acc[cv][j] = (floatx4){0.f, 0.f, 0.f, 0.f};
#pragma unroll
  for (int i = 0; i < 9; ++i) {
    int dy = i / 3, dx = i - dy * 3;
    float4 w0 = Wl[i * 96 + g];
    float4 w1 = Wl[1056 + i * 96 + g];
    float4 w2 = Wl[2112 + i * 96 + g];
#pragma unroll
    for (int j = 0; j < 4; ++j) {
      float4 t = tap[j + dy][dx];
      acc[0][j][0] += t.x * w0.x; acc[0][j][1] += t.y * w0.y;
      acc[0][j][2] += t.z * w0.z; acc[0][j][3] += t.w * w0.w;
      acc[1][j][0] += t.x * w1.x; acc[1][j][1] += t.y * w1.y;
      acc[1][j][2] += t.z * w1.z; acc[1][j][3] += t.w * w1.w;
      acc[2][j][0] += t.x * w2.x; acc[2][j][1] += t.y * w2.y;
      acc[2][j][2] += t.z * w2.z; acc[2][j][3] += t.w * w2.w;
    }
  }
  unsigned short* outs[3] = {qt, kt, vt};
  size_t o0 = ((size_t)b * 784 + y0 * 28 + xx) * 96 + g;   // us4 units
#pragma unroll
  for (int cv = 0; cv < 3; ++cv) {
    float4 inv = Wl[cv * 1056 + 864 + g];
    float4 sh  = Wl[cv * 1056 + 960 + g];
#pragma unroll
    for (int j = 0; j < 4; ++j) {
      us4 o;
      o.x = f2bf(acc[cv][j][0] * inv.x + sh.x);
      o.y = f2bf(acc[cv][j][1] * inv.y + sh.y);
      o.z = f2bf(acc[cv][j][2] * inv.z + sh.z);
      o.w = f2bf(acc[cv][j][3] * inv.w + sh.w);
      ((us4*)outs[cv])[o0 + (size_t)j * 28 * 96] = o;
    }
  }
}

// ---------------- 128x128 GEMM, merged QKV (mode 0, z-dispatch) / proj (mode 1) ------
// blockIdx (x,y) remapped XCD-chunked so the 3 nb-blocks sharing an A row-panel land
// on the same XCD's L2. Bijective for ANY z-phase.
// LDS shrunk 34816 -> 32768 B (epi1 repack uses XOR-swizzled [128][128] instead of
// pad-136): 163840/32768 = exactly 5 blocks/CU (was 4), matching the 20-wave VGPR cap.
__global__ __launch_bounds__(256) void gemm128_kernel(
    const unsigned short* __restrict__ A0, const unsigned short* __restrict__ A1,
    const unsigned short* __restrict__ A2, const unsigned short* __restrict__ wbf,
    const float* __restrict__ bias,
    unsigned short* __restrict__ qh, unsigned short* __restrict__ kh,
    unsigned short* __restrict__ vht, float* __restrict__ dout, int mode) {
  __shared__ __align__(16) unsigned short SB[16384];  // 32 KB: Al | Bl ; reused as Ct
  unsigned short* Al = SB;
  unsigned short* Bl = SB + 8192;
  const unsigned short* A;
  const unsigned short* W;
  int epi;
  float osc = 1.f;
  unsigned short* outb = nullptr;
  if (mode == 0) {
    int z = blockIdx.z;
    A = (z == 0) ? A0 : ((z == 1) ? A1 : A2);
    W = wbf + z * 147456;
    epi = (z == 2) ? 1 : 0;
    outb = (z == 0) ? qh : ((z == 1) ? kh : vht);
    if (z == 0) osc = SCALE_EXP2;        // fold softmax scale+log2e into Q
  } else {
    A = A0; W = wbf + 442368; epi = 2;
  }
  // bijective XCD-chunked remap of the (x,y) block space
  const int nwg  = gridDim.x * gridDim.y;
  const int orig = blockIdx.y * gridDim.x + blockIdx.x;
  const int qq = nwg >> 3, rr8 = nwg & 7;
  const int sft = (int)((unsigned)(blockIdx.z * nwg) & 7u);  // z-phase of linear id
  const int xcd = (orig + sft) & 7;                          // actual XCD of this block
  int base = 0;
  for (int c = 0; c < xcd; ++c) base += qq + ((((c - sft) & 7) < rr8) ? 1 : 0);
  const int nid = base + (orig >> 3);
  const int nb = (nid % gridDim.x) * 128, mb = (nid / gridDim.x) * 128;
  const int tid = threadIdx.x, lane = tid & 63;
  const int wid = tid >> 6;
  const int wr = wid >> 1, wc = wid & 1;
  const int quad = lane >> 4, l15 = lane & 15;
  floatx4 zf = {0.f, 0.f, 0.f, 0.f};
  floatx4 acc[4][4] = {{zf, zf, zf, zf}, {zf, zf, zf, zf},
                       {zf, zf, zf, zf}, {zf, zf, zf, zf}};
  for (int k0 = 0; k0 < 384; k0 += 64) {
#pragma unroll
    for (int i = 0; i < 4; ++i) {
      int chunk = tid + i * 256;
      int r = chunk >> 3, c8 = chunk & 7;
      int kcol = k0 + ((c8 ^ (r & 7)) * 8);
      async16(&A[(size_t)(mb + r) * 384 + kcol], &Al[((tid & 192) + i * 256) * 8]);
      async16(&W[(size_t)(nb + r) * 384 + kcol], &Bl[((tid & 192) + i * 256) * 8]);
    }
    __syncthreads();
    bhalf8 af[4][2], bf[4][2];
#pragma unroll
    for (int mi = 0; mi < 4; ++mi)
#pragma unroll
      for (int s = 0; s < 2; ++s) {
        int row = wr * 64 + mi * 16 + l15;
        af[mi][s] = *(const bhalf8*)&Al[row * 64 + (((s * 4 + quad) ^ (row & 7)) * 8)];
        int col = wc * 64 + mi * 16 + l15;
        bf[mi][s] = *(const bhalf8*)&Bl[col * 64 + (((s * 4 + quad) ^ (col & 7)) * 8)];
      }
#pragma unroll
    for (int mi = 0; mi < 4; ++mi)
#pragma unroll
      for (int ni = 0; ni < 4; ++ni) {
        acc[mi][ni] = MFMA16(af[mi][0], bf[ni][0], acc[mi][ni], 0, 0, 0);
        acc[mi][ni] = MFMA16(af[mi][1], bf[ni][1], acc[mi][ni], 0, 0, 0);
      }
    __syncthreads();
  }
  if (epi == 2) {
#pragma unroll
    for (int mi = 0; mi < 4; ++mi)
#pragma unroll
      for (int ni = 0; ni < 4; ++ni)
#pragma unroll
        for (int r = 0; r < 4; ++r) {
          int m = mb + wr * 64 + mi * 16 + quad * 4 + r;
          int n = nb + wc * 64 + ni * 16 + l15;
          dout[(size_t)m * 384 + n] = acc[mi][ni][r] + bias[n];
        }
  } else if (epi == 0) {
#pragma unroll
    for (int mi = 0; mi < 4; ++mi)
#pragma unroll
      for (int ni = 0; ni < 4; ++ni)
#pragma unroll
        for (int r = 0; r < 4; ++r) {
          int m = mb + wr * 64 + mi * 16 + quad * 4 + r;
          int n = nb + wc * 64 + ni * 16 + l15;
          int b = m / 784, t = m - b * 784;
          outb[(((size_t)b * 6 + (n >> 6)) * 784 + t) * 64 + (n & 63)] =
              f2bf(acc[mi][ni][r] * osc);
        }
  } else {
    // repack C -> Ct[n (row)][m], XOR-swizzled in 16-B chunks: ushorts ml'..ml'+7 of
    // row nl live at nl*128 + ((ml'>>3)^(nl&15))*8 + (ml'&7). Bijective per row;
    // read side applies the same chunk XOR -> coalesced b128 + global b128 stores.
#pragma unroll
    for (int mi = 0; mi < 4; ++mi)
#pragma unroll
      for (int ni = 0; ni < 4; ++ni) {
        int nl = wc * 64 + ni * 16 + l15;
        int ml = wr * 64 + mi * 16 + quad * 4;
        unsigned lo = ((unsigned)f2bf(acc[mi][ni][1]) << 16) | f2bf(acc[mi][ni][0]);
        unsigned hi = ((unsigned)f2bf(acc[mi][ni][3]) << 16) | f2bf(acc[mi][ni][2]);
        uint2 pk = {lo, hi};
        *(uint2*)&SB[nl * 128 + (((ml >> 3) ^ l15) << 3) + (ml & 7)] = pk;
      }
    __syncthreads();
#pragma unroll
    for (int p = 0; p < 8; ++p) {
      int idx = tid + p * 256;
      int row = idx >> 4, ck = idx & 15;
      int m0 = mb + ck * 8;
      int b = m0 / 784, t0 = m0 - b * 784;   // 784 % 8 == 0: chunk never straddles b
      bhalf8 vv = *(const bhalf8*)&SB[row * 128 + ((ck ^ (row & 15)) << 3)];
      *(bhalf8*)&vht[(size_t)b * 301056 + (size_t)(nb + row) * 784 + t0] = vv;
    }
  }
}

// -------- fused attention: P transposed in-register via permlane swaps, l via MFMA ----
// R5 exact shape (best measured: 49.5 us): 256 thr, KVBLK=64, 2x16KB dbuf, 0 conflicts,
// NO setprio (R9: -2 us -- no phase role-split in this structure, T5 regime absent).
__global__ __launch_bounds__(256, 4) void attn_kernel(
    const unsigned short* __restrict__ Q, const unsigned short* __restrict__ K,
    const unsigned short* __restrict__ Vt, unsigned short* __restrict__ O) {
  __shared__ __align__(16) unsigned short Kl[2][64 * 64];   // 16 KB
  __shared__ __align__(16) unsigned short Vl[2][64 * 64];   // 16 KB
  const int bh = blockIdx.x, qb = blockIdx.y * 128;
  const int tid = threadIdx.x, lane = tid & 63, wid = tid >> 6;
  const int quad = lane >> 4, l15 = lane & 15;
  const size_t hb = (size_t)bh * 50176;
  const unsigned short* Qh = Q + hb;
  const unsigned short* Kh = K + hb;
  const unsigned short* Vh = Vt + hb;  // [64][784]

  auto stage = [&](int kb2, int bufS) {
#pragma unroll
    for (int i = 0; i < 2; ++i) {
      int c = tid + i * 256;
      int tt = c >> 3, c8 = c & 7;
      int sw = (c8 ^ (tt & 7)) * 8;
      int row = kb2 + tt; if (row > 783) row = 783;
      async16(&Kh[(size_t)row * 64 + sw], &Kl[bufS][((tid & 192) + i * 256) * 8]);
      int col = kb2 + sw; if (col > 776) col = 776;
      async16(&Vh[(size_t)tt * 784 + col], &Vl[bufS][((tid & 192) + i * 256) * 8]);
    }
  };

  const int row0 = qb + wid * 32;           // wave's first q row
  const bool w0v = row0 < 784;              // wave has any valid rows (nt=0 tile)
  const bool w1v = (row0 + 16) < 784;       // nt=1 tile has valid rows

  bhalf8 zs = {0, 0, 0, 0, 0, 0, 0, 0};
  bhalf8 aq[2][2];  // Q as B-operand: lane n=q, k=d
#pragma unroll
  for (int nt = 0; nt < 2; ++nt) {
    int row = row0 + nt * 16 + l15;
#pragma unroll
    for (int d = 0; d < 2; ++d)
      aq[nt][d] = (row < 784) ? *(const bhalf8*)&Qh[(size_t)row * 64 + d * 32 + quad * 8]
                              : zs;
  }

  const bhalf8 ones = {16256, 16256, 16256, 16256, 16256, 16256, 16256, 16256};

  floatx4 zf = {0.f, 0.f, 0.f, 0.f};
  floatx4 accO[2][4] = {{zf, zf, zf, zf}, {zf, zf, zf, zf}};
  floatx4 accl[2] = {zf, zf};

  stage(0, 0);
  __syncthreads();

  for (int kt = 0; kt < 13; ++kt) {
    const int buf = kt & 1;
    const int kb = kt * 64;
    if (kt < 12) stage(kb + 64, buf ^ 1);

#pragma unroll
    for (int s = 0; s < 2; ++s) {
      if (kb + s * 32 >= 784) break;   // wave-uniform (last tile: only s=0 live)
      if (!w0v) continue;              // wave-uniform: no valid q rows -> skip compute
      const bool tok1 = (kb + s * 32 + 16) < 784;  // wave-uniform
      bhalf8 kk[2][2], vvs[4];
#pragma unroll
      for (int h = 0; h < 2; ++h)
#pragma unroll
        for (int d = 0; d < 2; ++d) {
          int tr = (2 * s + h) * 16 + l15;
          kk[h][d] = *(const bhalf8*)&Kl[buf][tr * 64 + (((d * 4 + quad) ^ (tr & 7)) * 8)];
        }
#pragma unroll
      for (int dt = 0; dt < 4; ++dt) {
        int dr = dt * 16 + l15;
        vvs[dt] = *(const bhalf8*)&Vl[buf][dr * 64 + (((s * 4 + quad) ^ (dr & 7)) * 8)];
      }
#pragma unroll
      for (int nt = 0; nt < 2; ++nt) {
        if (nt == 1 && !w1v) break;    // wave-uniform: nt=1 tile fully dead
        uint2 pk0 = {0u, 0u}, pk1 = {0u, 0u};
        {
          floatx4 sf = zf;
          sf = MFMA16(kk[0][0], aq[nt][0], sf, 0, 0, 0);
          sf = MFMA16(kk[0][1], aq[nt][1], sf, 0, 0, 0);
          pk0.x = __builtin_amdgcn_perm(fbits(__builtin_amdgcn_exp2f(sf[1])),
                                        fbits(__builtin_amdgcn_exp2f(sf[0])),
                                        0x07060302u);
          pk0.y = __builtin_amdgcn_perm(fbits(__builtin_amdgcn_exp2f(sf[3])),
                                        fbits(__builtin_amdgcn_exp2f(sf[2])),
                                        0x07060302u);
        }
        if (tok1) {
          floatx4 sf = zf;
          sf = MFMA16(kk[1][0], aq[nt][0], sf, 0, 0, 0);
          sf = MFMA16(kk[1][1], aq[nt][1], sf, 0, 0, 0);
          pk1.x = __builtin_amdgcn_perm(fbits(__builtin_amdgcn_exp2f(sf[1])),
                                        fbits(__builtin_amdgcn_exp2f(sf[0])),
                                        0x07060302u);
          pk1.y = __builtin_amdgcn_perm(fbits(__builtin_amdgcn_exp2f(sf[3])),
                                        fbits(__builtin_amdgcn_exp2f(sf[2])),
                                        0x07060302u);
        }
        // transpose P^T (C-layout) -> P (B-operand) fully in-register:
        //  t = permlane32_swap(a,b): t0={a.lo,b.lo}, t1={a.hi,b.hi}
        //  f = permlane16_swap(t0,t1): f0 rows={a.r0,a.r2,b.r0,b.r2},
        //                              f1 rows={a.r1,a.r3,b.r1,b.r3}
        auto sw0 = __builtin_amdgcn_permlane32_swap((int)pk0.x, (int)pk1.x, false, false);
        auto sw1 = __builtin_amdgcn_permlane32_swap((int)pk0.y, (int)pk1.y, false, false);
        auto f0 = __builtin_amdgcn_permlane16_swap(sw0[0], sw0[1], false, false);
        auto f1 = __builtin_amdgcn_permlane16_swap(sw1[0], sw1[1], false, false);
        union { uint4 u; bhalf8 v; } pf;
        pf.u.x = (unsigned)f0[0];
        pf.u.y = (unsigned)f1[0];
        pf.u.z = (unsigned)f0[1];
        pf.u.w = (unsigned)f1[1];
        accl[nt] = MFMA16(ones, pf.v, accl[nt], 0, 0, 0);
#pragma unroll
        for (int dt = 0; dt < 4; ++dt)
          accO[nt][dt] = MFMA16(vvs[dt], pf.v, accO[nt][dt], 0, 0, 0);
      }
    }
    __syncthreads();
  }

  const int b = bh / 6, h = bh - b * 6;
#pragma unroll
  for (int nt = 0; nt < 2; ++nt) {
    float iv = 1.f / accl[nt][0];
    int q = qb + wid * 32 + nt * 16 + l15;
    if (q < 784) {
#pragma unroll
      for (int dt = 0; dt < 4; ++dt) {
        us4 o;
        o.x = f2bf(accO[nt][dt][0] * iv);
        o.y = f2bf(accO[nt][dt][1] * iv);
        o.z = f2bf(accO[nt][dt][2] * iv);
        o.w = f2bf(accO[nt][dt][3] * iv);
        *(us4*)&O[((size_t)b * 784 + q) * 384 + h * 64 + dt * 16 + quad * 4] = o;
      }
    }
  }
}

extern "C" void kernel_launch(void* const* d_in, const int* in_sizes, int n_in,
                              void* d_out, int out_size, void* d_ws, size_t ws_size,
                              hipStream_t stream) {
  const float* x   = (const float*)d_in[0];
  const float* cwq = (const float*)d_in[3];
  const float* gq  = (const float*)d_in[4];
  const float* bq  = (const float*)d_in[5];
  const float* mq  = (const float*)d_in[6];
  const float* vq  = (const float*)d_in[7];
  const float* cwk = (const float*)d_in[8];
  const float* gk  = (const float*)d_in[9];
  const float* bk  = (const float*)d_in[10];
  const float* mk  = (const float*)d_in[11];
  const float* vk  = (const float*)d_in[12];
  const float* cwv = (const float*)d_in[13];
  const float* gv  = (const float*)d_in[14];
  const float* bv  = (const float*)d_in[15];
  const float* mv  = (const float*)d_in[16];
  const float* vv  = (const float*)d_in[17];
  const float* wq  = (const float*)d_in[18];
  const float* wk  = (const float*)d_in[19];
  const float* wv  = (const float*)d_in[20];
  const float* wp  = (const float*)d_in[21];
  const float* bp  = (const float*)d_in[22];

  unsigned short* ws = (unsigned short*)d_ws;
  const size_t SZ = (size_t)25088 * 384;
  unsigned short* qt  = ws;             // [25088,384] bf16; reused as attn out
  unsigned short* ktt = ws + SZ;
  unsigned short* vtt = ws + 2 * SZ;
  unsigned short* qh  = ws + 3 * SZ;    // [192][784][64]
  unsigned short* kh  = ws + 4 * SZ;
  unsigned short* vht = ws + 5 * SZ;    // [192][64][784]
  unsigned short* wbf = ws + 6 * SZ;    // 4 x [384,384] bf16
  float* fx = (float*)(ws + 5 * SZ);    // aliases vht: fx dead before vht written
  unsigned short* ob = qt;

  cvtw_prep_kernel<<<dim3(577), dim3(256), 0, stream>>>(
      wq, wk, wv, wp, wbf,
      cwq, gq, bq, mq, vq, cwk, gk, bk, mk, vk, cwv, gv, bv, mv, vv, fx);
  dwconv_bn_kernel<<<dim3(1568), dim3(384), 0, stream>>>(x, fx, qt, ktt, vtt);
  gemm128_kernel<<<dim3(3, 196, 3), dim3(256), 0, stream>>>(
      qt, ktt, vtt, wbf, bp, qh, kh, vht, (float*)d_out, 0);
  attn_kernel<<<dim3(192, 7), dim3(256), 0, stream>>>(qh, kh, vht, ob);
  gemm128_kernel<<<dim3(3, 196, 1), dim3(256), 0, stream>>>(
      ob, ktt, vtt, wbf, bp, qh, kh, vht, (float*)d_out, 1);
}